// Round 13
// baseline (269.213 us; speedup 1.0000x reference)
//
#include <hip/hip_runtime.h>

// NumericalBiasModule: out[e] = b2 + W2 · relu(W1 · rel(x[src], x[dst]) + b1)
// rel = [ratio | log_ratio | abs_diff | rel_diff], 128 features.
//
// MFMA tile (validated r4-r12): 16 edges/wave, mfma_f32_16x16x32_bf16.
// lane = (m=lane&15 edge, q=lane>>4 k-chunk); A-frag[j] = feat[m][q*8+j];
// C/D: col=lane&15 (hid), row=q*4+reg (edge).
//
// Structure (validated r12): packed node record (1 line/side: xh bf16[8] |
// xl8 u8[8] mantissa ext | lu8 u8[8] log-quant), weights in 20KB LDS image
// read just-in-time, depth-1 gather pipeline.
//
// Round-13 change (r12: VALU 57% busy but occupancy capped at 4 waves/SIMD
// by launch_bounds+LDS while VGPR=56 supports 8):
//  * 512-thread blocks, __launch_bounds__(512,8): 8 waves share ONE 20KB
//    LDS image -> 4 blocks/CU x 20KB = 80KB LDS, VGPR cap 64 >= 56,
//    8 waves/SIMD resident (2x TLP at zero register cost).
//  * log decode packs via truncation (pk_tr) not RNE: ~32 fewer VALU/tile
//    (adds <=0.07 abs err to a feature already quantized at 0.036).

#define DD    32
#define HID   64
#define RELF  128
#define EPSF  1e-8f
#define LXLO  -18.420681f          // log(1e-8)
#define LXSC  13.843137f           // 255 / 18.420681
#define LXIV  0.07223796f          // 18.420681 / 255
#define MSC   3.0517578125e-05f    // 2^-15

typedef short  bf16x8 __attribute__((ext_vector_type(8)));
typedef float  f32x4  __attribute__((ext_vector_type(4)));

union U8 { unsigned u[4]; bf16x8 v; uint4 q4; };
union Q  { uint4 v; unsigned u[4]; float f[4]; };

static __device__ __forceinline__ unsigned pk_tr(float lo, float hi) {
    return __builtin_amdgcn_perm(__builtin_bit_cast(unsigned, hi),
                                 __builtin_bit_cast(unsigned, lo), 0x07060302u);
}
static __device__ __forceinline__ unsigned rne_bits(float f) {
    unsigned u = __builtin_bit_cast(unsigned, f);
    return u + 0x7fffu + ((u >> 16) & 1u);
}
static __device__ __forceinline__ unsigned pk_rne(float lo, float hi) {
    return __builtin_amdgcn_perm(rne_bits(hi), rne_bits(lo), 0x07060302u);
}
static __device__ __forceinline__ float hi_f32(float f) {
    return __builtin_bit_cast(float, __builtin_bit_cast(unsigned, f) & 0xffff0000u);
}
static __device__ __forceinline__ float ubyte(unsigned w, int b) {
    return (float)((w >> (8 * b)) & 0xffu);   // folds to v_cvt_f32_ubyteN
}
static __device__ __forceinline__ unsigned q8(float v) {
    int u = (int)(v + 0.5f);
    return (unsigned)(u > 255 ? 255 : (u < 0 ? 0 : u));
}

// ---- prep: one thread per (node, q) 8-dim chunk ----
__global__ __launch_bounds__(256)
void prep_pack(const float* __restrict__ x, uint4* __restrict__ rec, int nchunk)
{
    int i = blockIdx.x * blockDim.x + threadIdx.x;   // chunk = node*4 + q
    if (i >= nchunk) return;
    const float4* xp = (const float4*)(x + (size_t)i * 8);
    float4 v0 = xp[0], v1 = xp[1];
    float xv[8] = {v0.x, v0.y, v0.z, v0.w, v1.x, v1.y, v1.z, v1.w};

    unsigned xh[4];
    #pragma unroll
    for (int p = 0; p < 4; ++p) xh[p] = pk_tr(xv[2*p], xv[2*p+1]);

    unsigned xl[2] = {0u, 0u}, lu[2] = {0u, 0u};
    #pragma unroll
    for (int e = 0; e < 8; ++e) {
        float a  = xv[e];
        float ah = hi_f32(a);
        float f  = 0.f;
        if (ah > 0.f)
            f = (a * __builtin_amdgcn_rcpf(ah) - 1.f) * 32768.f;   // 2^15
        xl[e >> 2] |= q8(f) << (8 * (e & 3));
        float lxe = __logf(a + EPSF);
        lu[e >> 2] |= q8((lxe - LXLO) * LXSC) << (8 * (e & 3));
    }

    uint4 r0; r0.x = xh[0]; r0.y = xh[1]; r0.z = xh[2]; r0.w = xh[3];
    uint4 r1; r1.x = xl[0]; r1.y = xl[1]; r1.z = lu[0]; r1.w = lu[1];
    rec[2 * i]     = r0;
    rec[2 * i + 1] = r1;
}

// PACK=1: packed records (2 lines/edge). PACK=0: raw x + per-edge logf.
template <int PACK>
__global__ __launch_bounds__(512, 8)
void edge_bias_mfma(const float* __restrict__ x,
                    const int*   __restrict__ ei,     // [2, E]
                    const float* __restrict__ W1,     // [64, 128]
                    const float* __restrict__ b1,
                    const float* __restrict__ W2,
                    const float* __restrict__ b2,
                    const uint4* __restrict__ rec,    // [N, 8] packed
                    float* __restrict__ out,
                    int E)
{
    const int lane = threadIdx.x & 63;
    const int wv   = threadIdx.x >> 6;                 // 0..7 within block
    const int wave = (blockIdx.x * blockDim.x + threadIdx.x) >> 6;
    const int nwv  = (gridDim.x * blockDim.x) >> 6;
    const int c = lane & 15;      // edge-in-tile (A) / hid-col (C)
    const int q = lane >> 4;      // k-chunk (A,B) / row-quad (C)

    // ---- LDS weight image: 5 sets x 4 nt = 20 frags x 1KB, shared by 8 waves ----
    // 0: W0h (ratio hi)  1: W0l (ratio lo)  2: WL (log)  3: WA  4: WD
    __shared__ uint4 sW[20 * 64];
    if (wv < 5) {
        const int s = wv;
        #pragma unroll
        for (int nt = 0; nt < 4; ++nt) {
            const float* wr = W1 + (nt * 16 + c) * RELF + q * 8;
            U8 t;
            if (s == 0) {
                #pragma unroll
                for (int p = 0; p < 4; ++p)
                    t.u[p] = pk_tr(wr[2*p], wr[2*p+1]);
            } else if (s == 1) {
                #pragma unroll
                for (int p = 0; p < 4; ++p) {
                    float w0 = wr[2*p], w1 = wr[2*p+1];
                    t.u[p] = pk_rne(w0 - hi_f32(w0), w1 - hi_f32(w1));
                }
            } else {
                const int base = (s == 2) ? 32 : (s == 3) ? 64 : 96;
                #pragma unroll
                for (int p = 0; p < 4; ++p)
                    t.u[p] = pk_rne(wr[base + 2*p], wr[base + 2*p + 1]);
            }
            sW[(s * 4 + nt) * 64 + lane] = t.q4;
        }
    }
    __syncthreads();

    float b1v[4], w2v[4];
    #pragma unroll
    for (int nt = 0; nt < 4; ++nt) {
        b1v[nt] = b1[nt * 16 + c];
        w2v[nt] = W2[nt * 16 + c];
    }
    const float b2s = b2[0];

    const int ntiles = (E + 15) >> 4;
    int t = wave;
    if (t >= ntiles) return;

    auto ldidx = [&](int tt_, int& s, int& d) {
        if (tt_ >= ntiles) tt_ = t;
        int em = (tt_ << 4) + c; if (em > E - 1) em = E - 1;
        s = ei[em]; d = ei[E + em];
    };
    auto gather = [&](int s, int d, Q& hi_, Q& mi_, Q& hj_, Q& mj_) {
        if constexpr (PACK) {
            const uint4* pi = rec + (size_t)s * 8 + q * 2;
            const uint4* pj = rec + (size_t)d * 8 + q * 2;
            hi_.v = pi[0]; mi_.v = pi[1];
            hj_.v = pj[0]; mj_.v = pj[1];
        } else {
            const uint4* pi = (const uint4*)(x + (size_t)s * DD + q * 8);
            const uint4* pj = (const uint4*)(x + (size_t)d * DD + q * 8);
            hi_.v = pi[0]; mi_.v = pi[1];
            hj_.v = pj[0]; mj_.v = pj[1];
        }
    };
    // decode one packed side -> 8 fp32 x + bf16 log A-frag
    auto decode = [&](const Q& h, const Q& m, float* xv, bf16x8& lfrag) {
        #pragma unroll
        for (int p = 0; p < 4; ++p) {
            float lo = __builtin_bit_cast(float, h.u[p] << 16);
            float hi = __builtin_bit_cast(float, h.u[p] & 0xffff0000u);
            unsigned xb = (p < 2) ? m.u[0] : m.u[1];
            float m0 = ubyte(xb, (2 * p) & 3);
            float m1 = ubyte(xb, (2 * p + 1) & 3);
            xv[2 * p]     = fmaf(lo * MSC, m0, lo);
            xv[2 * p + 1] = fmaf(hi * MSC, m1, hi);
        }
        U8 L;
        #pragma unroll
        for (int p = 0; p < 4; ++p) {
            unsigned lb = (p < 2) ? m.u[2] : m.u[3];
            float l0 = fmaf(ubyte(lb, (2 * p) & 3),     LXIV, LXLO);
            float l1 = fmaf(ubyte(lb, (2 * p + 1) & 3), LXIV, LXLO);
            L.u[p] = pk_tr(l0, l1);   // truncate: lx already quantized at 0.036
        }
        lfrag = L.v;
    };

    auto compute = [&](int tc, const Q& hI, const Q& mI, const Q& hJ, const Q& mJ) {
        float xiv[8], xjv[8];
        bf16x8 aLi, aLj;
        if constexpr (PACK) {
            decode(hI, mI, xiv, aLi);
            decode(hJ, mJ, xjv, aLj);
        } else {
            #pragma unroll
            for (int p = 0; p < 4; ++p) { xiv[p] = hI.f[p]; xiv[4 + p] = mI.f[p]; }
            #pragma unroll
            for (int p = 0; p < 4; ++p) { xjv[p] = hJ.f[p]; xjv[4 + p] = mJ.f[p]; }
            U8 ti, tj;
            #pragma unroll
            for (int p = 0; p < 4; ++p) {
                ti.u[p] = pk_rne(__logf(xiv[2*p] + EPSF), __logf(xiv[2*p+1] + EPSF));
                tj.u[p] = pk_rne(__logf(xjv[2*p] + EPSF), __logf(xjv[2*p+1] + EPSF));
            }
            aLi = ti.v; aLj = tj.v;
        }
        // -lxj: bf16 sign flip on the A side (replaces a WLn weight set)
        U8 nj; nj.v = aLj;
        #pragma unroll
        for (int p = 0; p < 4; ++p) nj.u[p] ^= 0x80008000u;

        U8 R, Rl, Aa, Dd;
        #pragma unroll
        for (int p = 0; p < 4; ++p) {
            float a0 = xiv[2*p], a1 = xiv[2*p+1];
            float c0 = xjv[2*p], c1 = xjv[2*p+1];
            float r0 = a0 * __builtin_amdgcn_rcpf(c0 + EPSF);
            float r1 = a1 * __builtin_amdgcn_rcpf(c1 + EPSF);
            float d0 = fabsf(a0 - c0), d1 = fabsf(a1 - c1);
            float g0 = d0 * __builtin_amdgcn_rcpf(fmaxf(a0, c0) + EPSF);
            float g1 = d1 * __builtin_amdgcn_rcpf(fmaxf(a1, c1) + EPSF);
            R.u[p]  = pk_tr(r0, r1);
            Rl.u[p] = pk_tr(r0 - hi_f32(r0), r1 - hi_f32(r1));
            Aa.u[p] = pk_tr(d0, d1);
            Dd.u[p] = pk_tr(g0, g1);
        }

        // opaque offset: stops LICM hoisting weight ds_reads into registers
        int off = lane;
        asm volatile("" : "+v"(off));
        auto ldfrag = [&](int s, int nt) {
            U8 w; w.q4 = sW[(s * 4 + nt) * 64 + off];
            return w.v;
        };

        f32x4 acc[4];
        #pragma unroll
        for (int nt = 0; nt < 4; ++nt) {
            acc[nt][0] = b1v[nt]; acc[nt][1] = b1v[nt];
            acc[nt][2] = b1v[nt]; acc[nt][3] = b1v[nt];
        }
        #pragma unroll
        for (int nt = 0; nt < 4; ++nt) {
            bf16x8 fW0h = ldfrag(0, nt);
            bf16x8 fW0l = ldfrag(1, nt);
            bf16x8 fWL  = ldfrag(2, nt);
            bf16x8 fWA  = ldfrag(3, nt);
            bf16x8 fWD  = ldfrag(4, nt);
            acc[nt] = __builtin_amdgcn_mfma_f32_16x16x32_bf16(R.v,  fW0h, acc[nt], 0, 0, 0);
            acc[nt] = __builtin_amdgcn_mfma_f32_16x16x32_bf16(Rl.v, fW0h, acc[nt], 0, 0, 0);
            acc[nt] = __builtin_amdgcn_mfma_f32_16x16x32_bf16(R.v,  fW0l, acc[nt], 0, 0, 0);
            acc[nt] = __builtin_amdgcn_mfma_f32_16x16x32_bf16(aLi,  fWL,  acc[nt], 0, 0, 0);
            acc[nt] = __builtin_amdgcn_mfma_f32_16x16x32_bf16(nj.v, fWL,  acc[nt], 0, 0, 0);
            acc[nt] = __builtin_amdgcn_mfma_f32_16x16x32_bf16(Aa.v, fWA,  acc[nt], 0, 0, 0);
            acc[nt] = __builtin_amdgcn_mfma_f32_16x16x32_bf16(Dd.v, fWD,  acc[nt], 0, 0, 0);
        }

        float p[4];
        #pragma unroll
        for (int r = 0; r < 4; ++r) {
            float pp = 0.f;
            #pragma unroll
            for (int nt = 0; nt < 4; ++nt)
                pp = fmaf(fmaxf(acc[nt][r], 0.f), w2v[nt], pp);
            pp += __shfl_xor(pp, 1);
            pp += __shfl_xor(pp, 2);
            pp += __shfl_xor(pp, 4);
            pp += __shfl_xor(pp, 8);
            p[r] = pp;
        }
        if (c < 4) {
            const int e = (tc << 4) + q * 4 + c;
            if (e < E) {
                float v = (c == 0) ? p[0] : (c == 1) ? p[1] : (c == 2) ? p[2] : p[3];
                out[e] = v + b2s;
            }
        }
    };

    // ---- depth-1 pipeline: idx 2 ahead, gathers 1 ahead ----
    Q hiC, miC, hjC, mjC;
    int srcN, dstN;
    { int s, d; ldidx(t, s, d); gather(s, d, hiC, miC, hjC, mjC); }
    ldidx(t + nwv, srcN, dstN);

    for (; t < ntiles; t += nwv) {
        Q hiN, miN, hjN, mjN;
        gather(srcN, dstN, hiN, miN, hjN, mjN);       // tile t+nwv
        int srcN2, dstN2;
        ldidx(t + 2 * nwv, srcN2, dstN2);

        compute(t, hiC, miC, hjC, mjC);

        hiC = hiN; miC = miN; hjC = hjN; mjC = mjN;
        srcN = srcN2; dstN = dstN2;
    }
}

extern "C" void kernel_launch(void* const* d_in, const int* in_sizes, int n_in,
                              void* d_out, int out_size, void* d_ws, size_t ws_size,
                              hipStream_t stream)
{
    const float* x   = (const float*)d_in[0];
    const int*   ei  = (const int*)  d_in[1];
    const float* W1  = (const float*)d_in[2];
    const float* b1  = (const float*)d_in[3];
    const float* W2  = (const float*)d_in[4];
    const float* b2  = (const float*)d_in[5];
    float* out = (float*)d_out;

    const int E  = out_size;       // 1,000,000
    const int Nd = in_sizes[0];    // N*D = 3,200,000
    uint4* rec = (uint4*)d_ws;     // N * 128 bytes = Nd * 4 bytes

    const bool pack = ws_size >= (size_t)Nd * 4 && (Nd % 8) == 0;
    if (pack) {
        const int nchunk = Nd / 8;
        prep_pack<<<(nchunk + 255) / 256, 256, 0, stream>>>(x, rec, nchunk);
        // 2048 blocks x 512 = 16384 waves (3.8 tiles/wave); 8 waves/SIMD resident
        edge_bias_mfma<1><<<2048, 512, 0, stream>>>(x, ei, W1, b1, W2, b2, rec, out, E);
    } else {
        edge_bias_mfma<0><<<2048, 512, 0, stream>>>(x, ei, W1, b1, W2, b2, rec, out, E);
    }
}

// Round 14
// 174.928 us; speedup vs baseline: 1.5390x; 1.5390x over previous
//
#include <hip/hip_runtime.h>

// NumericalBiasModule: out[e] = b2 + W2 · relu(W1 · rel(x[src], x[dst]) + b1)
// rel = [ratio | log_ratio | abs_diff | rel_diff], 128 features.
//
// MFMA tile (validated r4-r12): 16 edges/wave, mfma_f32_16x16x32_bf16.
// lane = (m=lane&15 edge, q=lane>>4 k-chunk); A-frag[j] = feat[m][q*8+j];
// C/D: col=lane&15 (hid), row=q*4+reg (edge).
//
// Structure (validated r12, 72us): packed node record (1 line/side:
// xh bf16[8] | xl8 u8[8] mantissa ext | lu8 u8[8] log-quant), weights in a
// 20KB LDS image read just-in-time, depth-1 gather pipeline.
//
// Round-14 (r13 post-mortem: launch_bounds(512,8) VGPR cap=64 < working set
// -> allocator went to 32 regs + full scratch spill, 360MB WRITE, 198us):
//   __launch_bounds__(256, 6): VGPR cap 85 (>= 56 measured + slack, no
//   spill), LDS 6 x 20KB = 120KB <= 160KB -> 6 waves/SIMD (r12 had 4).
//   Everything else identical to r12 (+ r13's pk_tr log-decode trim,
//   absmax-validated at 2.0).

#define DD    32
#define HID   64
#define RELF  128
#define EPSF  1e-8f
#define LXLO  -18.420681f          // log(1e-8)
#define LXSC  13.843137f           // 255 / 18.420681
#define LXIV  0.07223796f          // 18.420681 / 255
#define MSC   3.0517578125e-05f    // 2^-15

typedef short  bf16x8 __attribute__((ext_vector_type(8)));
typedef float  f32x4  __attribute__((ext_vector_type(4)));

union U8 { unsigned u[4]; bf16x8 v; uint4 q4; };
union Q  { uint4 v; unsigned u[4]; float f[4]; };

static __device__ __forceinline__ unsigned pk_tr(float lo, float hi) {
    return __builtin_amdgcn_perm(__builtin_bit_cast(unsigned, hi),
                                 __builtin_bit_cast(unsigned, lo), 0x07060302u);
}
static __device__ __forceinline__ unsigned rne_bits(float f) {
    unsigned u = __builtin_bit_cast(unsigned, f);
    return u + 0x7fffu + ((u >> 16) & 1u);
}
static __device__ __forceinline__ unsigned pk_rne(float lo, float hi) {
    return __builtin_amdgcn_perm(rne_bits(hi), rne_bits(lo), 0x07060302u);
}
static __device__ __forceinline__ float hi_f32(float f) {
    return __builtin_bit_cast(float, __builtin_bit_cast(unsigned, f) & 0xffff0000u);
}
static __device__ __forceinline__ float ubyte(unsigned w, int b) {
    return (float)((w >> (8 * b)) & 0xffu);   // folds to v_cvt_f32_ubyteN
}
static __device__ __forceinline__ unsigned q8(float v) {
    int u = (int)(v + 0.5f);
    return (unsigned)(u > 255 ? 255 : (u < 0 ? 0 : u));
}

// ---- prep: one thread per (node, q) 8-dim chunk ----
__global__ __launch_bounds__(256)
void prep_pack(const float* __restrict__ x, uint4* __restrict__ rec, int nchunk)
{
    int i = blockIdx.x * blockDim.x + threadIdx.x;   // chunk = node*4 + q
    if (i >= nchunk) return;
    const float4* xp = (const float4*)(x + (size_t)i * 8);
    float4 v0 = xp[0], v1 = xp[1];
    float xv[8] = {v0.x, v0.y, v0.z, v0.w, v1.x, v1.y, v1.z, v1.w};

    unsigned xh[4];
    #pragma unroll
    for (int p = 0; p < 4; ++p) xh[p] = pk_tr(xv[2*p], xv[2*p+1]);

    unsigned xl[2] = {0u, 0u}, lu[2] = {0u, 0u};
    #pragma unroll
    for (int e = 0; e < 8; ++e) {
        float a  = xv[e];
        float ah = hi_f32(a);
        float f  = 0.f;
        if (ah > 0.f)
            f = (a * __builtin_amdgcn_rcpf(ah) - 1.f) * 32768.f;   // 2^15
        xl[e >> 2] |= q8(f) << (8 * (e & 3));
        float lxe = __logf(a + EPSF);
        lu[e >> 2] |= q8((lxe - LXLO) * LXSC) << (8 * (e & 3));
    }

    uint4 r0; r0.x = xh[0]; r0.y = xh[1]; r0.z = xh[2]; r0.w = xh[3];
    uint4 r1; r1.x = xl[0]; r1.y = xl[1]; r1.z = lu[0]; r1.w = lu[1];
    rec[2 * i]     = r0;
    rec[2 * i + 1] = r1;
}

// PACK=1: packed records (2 lines/edge). PACK=0: raw x + per-edge logf.
template <int PACK>
__global__ __launch_bounds__(256, 6)
void edge_bias_mfma(const float* __restrict__ x,
                    const int*   __restrict__ ei,     // [2, E]
                    const float* __restrict__ W1,     // [64, 128]
                    const float* __restrict__ b1,
                    const float* __restrict__ W2,
                    const float* __restrict__ b2,
                    const uint4* __restrict__ rec,    // [N, 8] packed
                    float* __restrict__ out,
                    int E)
{
    const int lane = threadIdx.x & 63;
    const int wv   = threadIdx.x >> 6;
    const int wave = (blockIdx.x * blockDim.x + threadIdx.x) >> 6;
    const int nwv  = (gridDim.x * blockDim.x) >> 6;
    const int c = lane & 15;      // edge-in-tile (A) / hid-col (C)
    const int q = lane >> 4;      // k-chunk (A,B) / row-quad (C)

    // ---- LDS weight image: 5 sets x 4 nt = 20 frags x 1KB (r11/r12) ----
    // 0: W0h (ratio hi)  1: W0l (ratio lo)  2: WL (log)  3: WA  4: WD
    __shared__ uint4 sW[20 * 64];
    for (int s = wv; s < 5; s += 4) {
        #pragma unroll
        for (int nt = 0; nt < 4; ++nt) {
            const float* wr = W1 + (nt * 16 + c) * RELF + q * 8;
            U8 t;
            if (s == 0) {
                #pragma unroll
                for (int p = 0; p < 4; ++p)
                    t.u[p] = pk_tr(wr[2*p], wr[2*p+1]);
            } else if (s == 1) {
                #pragma unroll
                for (int p = 0; p < 4; ++p) {
                    float w0 = wr[2*p], w1 = wr[2*p+1];
                    t.u[p] = pk_rne(w0 - hi_f32(w0), w1 - hi_f32(w1));
                }
            } else {
                const int base = (s == 2) ? 32 : (s == 3) ? 64 : 96;
                #pragma unroll
                for (int p = 0; p < 4; ++p)
                    t.u[p] = pk_rne(wr[base + 2*p], wr[base + 2*p + 1]);
            }
            sW[(s * 4 + nt) * 64 + lane] = t.q4;
        }
    }
    __syncthreads();

    float b1v[4], w2v[4];
    #pragma unroll
    for (int nt = 0; nt < 4; ++nt) {
        b1v[nt] = b1[nt * 16 + c];
        w2v[nt] = W2[nt * 16 + c];
    }
    const float b2s = b2[0];

    const int ntiles = (E + 15) >> 4;
    int t = wave;
    if (t >= ntiles) return;

    auto ldidx = [&](int tt_, int& s, int& d) {
        if (tt_ >= ntiles) tt_ = t;
        int em = (tt_ << 4) + c; if (em > E - 1) em = E - 1;
        s = ei[em]; d = ei[E + em];
    };
    auto gather = [&](int s, int d, Q& hi_, Q& mi_, Q& hj_, Q& mj_) {
        if constexpr (PACK) {
            const uint4* pi = rec + (size_t)s * 8 + q * 2;
            const uint4* pj = rec + (size_t)d * 8 + q * 2;
            hi_.v = pi[0]; mi_.v = pi[1];
            hj_.v = pj[0]; mj_.v = pj[1];
        } else {
            const uint4* pi = (const uint4*)(x + (size_t)s * DD + q * 8);
            const uint4* pj = (const uint4*)(x + (size_t)d * DD + q * 8);
            hi_.v = pi[0]; mi_.v = pi[1];
            hj_.v = pj[0]; mj_.v = pj[1];
        }
    };
    // decode one packed side -> 8 fp32 x + bf16 log A-frag
    auto decode = [&](const Q& h, const Q& m, float* xv, bf16x8& lfrag) {
        #pragma unroll
        for (int p = 0; p < 4; ++p) {
            float lo = __builtin_bit_cast(float, h.u[p] << 16);
            float hi = __builtin_bit_cast(float, h.u[p] & 0xffff0000u);
            unsigned xb = (p < 2) ? m.u[0] : m.u[1];
            float m0 = ubyte(xb, (2 * p) & 3);
            float m1 = ubyte(xb, (2 * p + 1) & 3);
            xv[2 * p]     = fmaf(lo * MSC, m0, lo);
            xv[2 * p + 1] = fmaf(hi * MSC, m1, hi);
        }
        U8 L;
        #pragma unroll
        for (int p = 0; p < 4; ++p) {
            unsigned lb = (p < 2) ? m.u[2] : m.u[3];
            float l0 = fmaf(ubyte(lb, (2 * p) & 3),     LXIV, LXLO);
            float l1 = fmaf(ubyte(lb, (2 * p + 1) & 3), LXIV, LXLO);
            L.u[p] = pk_tr(l0, l1);   // truncate: lx already quantized at 0.036
        }
        lfrag = L.v;
    };

    auto compute = [&](int tc, const Q& hI, const Q& mI, const Q& hJ, const Q& mJ) {
        float xiv[8], xjv[8];
        bf16x8 aLi, aLj;
        if constexpr (PACK) {
            decode(hI, mI, xiv, aLi);
            decode(hJ, mJ, xjv, aLj);
        } else {
            #pragma unroll
            for (int p = 0; p < 4; ++p) { xiv[p] = hI.f[p]; xiv[4 + p] = mI.f[p]; }
            #pragma unroll
            for (int p = 0; p < 4; ++p) { xjv[p] = hJ.f[p]; xjv[4 + p] = mJ.f[p]; }
            U8 ti, tj;
            #pragma unroll
            for (int p = 0; p < 4; ++p) {
                ti.u[p] = pk_rne(__logf(xiv[2*p] + EPSF), __logf(xiv[2*p+1] + EPSF));
                tj.u[p] = pk_rne(__logf(xjv[2*p] + EPSF), __logf(xjv[2*p+1] + EPSF));
            }
            aLi = ti.v; aLj = tj.v;
        }
        // -lxj: bf16 sign flip on the A side (replaces a WLn weight set)
        U8 nj; nj.v = aLj;
        #pragma unroll
        for (int p = 0; p < 4; ++p) nj.u[p] ^= 0x80008000u;

        U8 R, Rl, Aa, Dd;
        #pragma unroll
        for (int p = 0; p < 4; ++p) {
            float a0 = xiv[2*p], a1 = xiv[2*p+1];
            float c0 = xjv[2*p], c1 = xjv[2*p+1];
            float r0 = a0 * __builtin_amdgcn_rcpf(c0 + EPSF);
            float r1 = a1 * __builtin_amdgcn_rcpf(c1 + EPSF);
            float d0 = fabsf(a0 - c0), d1 = fabsf(a1 - c1);
            float g0 = d0 * __builtin_amdgcn_rcpf(fmaxf(a0, c0) + EPSF);
            float g1 = d1 * __builtin_amdgcn_rcpf(fmaxf(a1, c1) + EPSF);
            R.u[p]  = pk_tr(r0, r1);
            Rl.u[p] = pk_tr(r0 - hi_f32(r0), r1 - hi_f32(r1));
            Aa.u[p] = pk_tr(d0, d1);
            Dd.u[p] = pk_tr(g0, g1);
        }

        // opaque offset: stops LICM hoisting weight ds_reads into registers
        int off = lane;
        asm volatile("" : "+v"(off));
        auto ldfrag = [&](int s, int nt) {
            U8 w; w.q4 = sW[(s * 4 + nt) * 64 + off];
            return w.v;
        };

        f32x4 acc[4];
        #pragma unroll
        for (int nt = 0; nt < 4; ++nt) {
            acc[nt][0] = b1v[nt]; acc[nt][1] = b1v[nt];
            acc[nt][2] = b1v[nt]; acc[nt][3] = b1v[nt];
        }
        #pragma unroll
        for (int nt = 0; nt < 4; ++nt) {
            bf16x8 fW0h = ldfrag(0, nt);
            bf16x8 fW0l = ldfrag(1, nt);
            bf16x8 fWL  = ldfrag(2, nt);
            bf16x8 fWA  = ldfrag(3, nt);
            bf16x8 fWD  = ldfrag(4, nt);
            acc[nt] = __builtin_amdgcn_mfma_f32_16x16x32_bf16(R.v,  fW0h, acc[nt], 0, 0, 0);
            acc[nt] = __builtin_amdgcn_mfma_f32_16x16x32_bf16(Rl.v, fW0h, acc[nt], 0, 0, 0);
            acc[nt] = __builtin_amdgcn_mfma_f32_16x16x32_bf16(R.v,  fW0l, acc[nt], 0, 0, 0);
            acc[nt] = __builtin_amdgcn_mfma_f32_16x16x32_bf16(aLi,  fWL,  acc[nt], 0, 0, 0);
            acc[nt] = __builtin_amdgcn_mfma_f32_16x16x32_bf16(nj.v, fWL,  acc[nt], 0, 0, 0);
            acc[nt] = __builtin_amdgcn_mfma_f32_16x16x32_bf16(Aa.v, fWA,  acc[nt], 0, 0, 0);
            acc[nt] = __builtin_amdgcn_mfma_f32_16x16x32_bf16(Dd.v, fWD,  acc[nt], 0, 0, 0);
        }

        float p[4];
        #pragma unroll
        for (int r = 0; r < 4; ++r) {
            float pp = 0.f;
            #pragma unroll
            for (int nt = 0; nt < 4; ++nt)
                pp = fmaf(fmaxf(acc[nt][r], 0.f), w2v[nt], pp);
            pp += __shfl_xor(pp, 1);
            pp += __shfl_xor(pp, 2);
            pp += __shfl_xor(pp, 4);
            pp += __shfl_xor(pp, 8);
            p[r] = pp;
        }
        if (c < 4) {
            const int e = (tc << 4) + q * 4 + c;
            if (e < E) {
                float v = (c == 0) ? p[0] : (c == 1) ? p[1] : (c == 2) ? p[2] : p[3];
                out[e] = v + b2s;
            }
        }
    };

    // ---- depth-1 pipeline: idx 2 ahead, gathers 1 ahead ----
    Q hiC, miC, hjC, mjC;
    int srcN, dstN;
    { int s, d; ldidx(t, s, d); gather(s, d, hiC, miC, hjC, mjC); }
    ldidx(t + nwv, srcN, dstN);

    for (; t < ntiles; t += nwv) {
        Q hiN, miN, hjN, mjN;
        gather(srcN, dstN, hiN, miN, hjN, mjN);       // tile t+nwv
        int srcN2, dstN2;
        ldidx(t + 2 * nwv, srcN2, dstN2);

        compute(t, hiC, miC, hjC, mjC);

        hiC = hiN; miC = miN; hjC = hjN; mjC = mjN;
        srcN = srcN2; dstN = dstN2;
    }
}

extern "C" void kernel_launch(void* const* d_in, const int* in_sizes, int n_in,
                              void* d_out, int out_size, void* d_ws, size_t ws_size,
                              hipStream_t stream)
{
    const float* x   = (const float*)d_in[0];
    const int*   ei  = (const int*)  d_in[1];
    const float* W1  = (const float*)d_in[2];
    const float* b1  = (const float*)d_in[3];
    const float* W2  = (const float*)d_in[4];
    const float* b2  = (const float*)d_in[5];
    float* out = (float*)d_out;

    const int E  = out_size;       // 1,000,000
    const int Nd = in_sizes[0];    // N*D = 3,200,000
    uint4* rec = (uint4*)d_ws;     // N * 128 bytes = Nd * 4 bytes

    const bool pack = ws_size >= (size_t)Nd * 4 && (Nd % 8) == 0;
    if (pack) {
        const int nchunk = Nd / 8;
        prep_pack<<<(nchunk + 255) / 256, 256, 0, stream>>>(x, rec, nchunk);
        // 2048 blocks x 256: 8192 waves, 7.6 tiles/wave; 6 blocks/CU resident
        edge_bias_mfma<1><<<2048, 256, 0, stream>>>(x, ei, W1, b1, W2, b2, rec, out, E);
    } else {
        edge_bias_mfma<0><<<2048, 256, 0, stream>>>(x, ei, W1, b1, W2, b2, rec, out, E);
    }
}

// Round 15
// 146.724 us; speedup vs baseline: 1.8348x; 1.1922x over previous
//
#include <hip/hip_runtime.h>

// NumericalBiasModule: out[e] = b2 + W2 · relu(W1 · rel(x[src], x[dst]) + b1)
// rel = [ratio | log_ratio | abs_diff | rel_diff], 128 features.
//
// MFMA tile (validated r4-r12): 16 edges/wave, mfma_f32_16x16x32_bf16.
// lane = (m=lane&15 edge, q=lane>>4 k-chunk); A-frag[j] = feat[m][q*8+j];
// C/D: col=lane&15 (hid), row=q*4+reg (edge).
//
// Structure (validated r12, 72us kernel): packed node record (1 line/side:
// xh bf16[8] | xl8 u8[8] mantissa ext | lu8 u8[8] log-quant), weights in a
// 20KB LDS image read just-in-time.
//
// Round-15 (r13/r14 post-mortem: launch_bounds min-waves 8/6 with the
// pipelined working set (~80 combined VGPR+AGPR) hits the allocator cliff ->
// scratch spill. r12 arithmetic says VALU/tile/wave ~575cyc, so ~6 waves
// saturate VALU -> floor ~45-50us. Fix: SHRINK the working set to fit the
// 6-wave cap instead of lowering the cap onto a fat kernel):
//   * software pipeline REMOVED (serial gather->compute; at 6 waves TLP
//     replaces ILP -- r8 already showed depth is useless when wave-starved,
//     and depth buffers cost ~16-20 regs).
//   * only a 2-register idx prefetch kept (trims idx latency off the chain).
//   * __launch_bounds__(256, 6): cap 85 >> ~60-reg working set.

#define DD    32
#define HID   64
#define RELF  128
#define EPSF  1e-8f
#define LXLO  -18.420681f          // log(1e-8)
#define LXSC  13.843137f           // 255 / 18.420681
#define LXIV  0.07223796f          // 18.420681 / 255
#define MSC   3.0517578125e-05f    // 2^-15

typedef short  bf16x8 __attribute__((ext_vector_type(8)));
typedef float  f32x4  __attribute__((ext_vector_type(4)));

union U8 { unsigned u[4]; bf16x8 v; uint4 q4; };
union Q  { uint4 v; unsigned u[4]; float f[4]; };

static __device__ __forceinline__ unsigned pk_tr(float lo, float hi) {
    return __builtin_amdgcn_perm(__builtin_bit_cast(unsigned, hi),
                                 __builtin_bit_cast(unsigned, lo), 0x07060302u);
}
static __device__ __forceinline__ unsigned rne_bits(float f) {
    unsigned u = __builtin_bit_cast(unsigned, f);
    return u + 0x7fffu + ((u >> 16) & 1u);
}
static __device__ __forceinline__ unsigned pk_rne(float lo, float hi) {
    return __builtin_amdgcn_perm(rne_bits(hi), rne_bits(lo), 0x07060302u);
}
static __device__ __forceinline__ float hi_f32(float f) {
    return __builtin_bit_cast(float, __builtin_bit_cast(unsigned, f) & 0xffff0000u);
}
static __device__ __forceinline__ float ubyte(unsigned w, int b) {
    return (float)((w >> (8 * b)) & 0xffu);   // folds to v_cvt_f32_ubyteN
}
static __device__ __forceinline__ unsigned q8(float v) {
    int u = (int)(v + 0.5f);
    return (unsigned)(u > 255 ? 255 : (u < 0 ? 0 : u));
}

// ---- prep: one thread per (node, q) 8-dim chunk ----
__global__ __launch_bounds__(256)
void prep_pack(const float* __restrict__ x, uint4* __restrict__ rec, int nchunk)
{
    int i = blockIdx.x * blockDim.x + threadIdx.x;   // chunk = node*4 + q
    if (i >= nchunk) return;
    const float4* xp = (const float4*)(x + (size_t)i * 8);
    float4 v0 = xp[0], v1 = xp[1];
    float xv[8] = {v0.x, v0.y, v0.z, v0.w, v1.x, v1.y, v1.z, v1.w};

    unsigned xh[4];
    #pragma unroll
    for (int p = 0; p < 4; ++p) xh[p] = pk_tr(xv[2*p], xv[2*p+1]);

    unsigned xl[2] = {0u, 0u}, lu[2] = {0u, 0u};
    #pragma unroll
    for (int e = 0; e < 8; ++e) {
        float a  = xv[e];
        float ah = hi_f32(a);
        float f  = 0.f;
        if (ah > 0.f)
            f = (a * __builtin_amdgcn_rcpf(ah) - 1.f) * 32768.f;   // 2^15
        xl[e >> 2] |= q8(f) << (8 * (e & 3));
        float lxe = __logf(a + EPSF);
        lu[e >> 2] |= q8((lxe - LXLO) * LXSC) << (8 * (e & 3));
    }

    uint4 r0; r0.x = xh[0]; r0.y = xh[1]; r0.z = xh[2]; r0.w = xh[3];
    uint4 r1; r1.x = xl[0]; r1.y = xl[1]; r1.z = lu[0]; r1.w = lu[1];
    rec[2 * i]     = r0;
    rec[2 * i + 1] = r1;
}

// PACK=1: packed records (2 lines/edge). PACK=0: raw x + per-edge logf.
template <int PACK>
__global__ __launch_bounds__(256, 6)
void edge_bias_mfma(const float* __restrict__ x,
                    const int*   __restrict__ ei,     // [2, E]
                    const float* __restrict__ W1,     // [64, 128]
                    const float* __restrict__ b1,
                    const float* __restrict__ W2,
                    const float* __restrict__ b2,
                    const uint4* __restrict__ rec,    // [N, 8] packed
                    float* __restrict__ out,
                    int E)
{
    const int lane = threadIdx.x & 63;
    const int wv   = threadIdx.x >> 6;
    const int wave = (blockIdx.x * blockDim.x + threadIdx.x) >> 6;
    const int nwv  = (gridDim.x * blockDim.x) >> 6;
    const int c = lane & 15;      // edge-in-tile (A) / hid-col (C)
    const int q = lane >> 4;      // k-chunk (A,B) / row-quad (C)

    // ---- LDS weight image: 5 sets x 4 nt = 20 frags x 1KB (r11/r12) ----
    // 0: W0h (ratio hi)  1: W0l (ratio lo)  2: WL (log)  3: WA  4: WD
    __shared__ uint4 sW[20 * 64];
    for (int s = wv; s < 5; s += 4) {
        #pragma unroll
        for (int nt = 0; nt < 4; ++nt) {
            const float* wr = W1 + (nt * 16 + c) * RELF + q * 8;
            U8 t;
            if (s == 0) {
                #pragma unroll
                for (int p = 0; p < 4; ++p)
                    t.u[p] = pk_tr(wr[2*p], wr[2*p+1]);
            } else if (s == 1) {
                #pragma unroll
                for (int p = 0; p < 4; ++p) {
                    float w0 = wr[2*p], w1 = wr[2*p+1];
                    t.u[p] = pk_rne(w0 - hi_f32(w0), w1 - hi_f32(w1));
                }
            } else {
                const int base = (s == 2) ? 32 : (s == 3) ? 64 : 96;
                #pragma unroll
                for (int p = 0; p < 4; ++p)
                    t.u[p] = pk_rne(wr[base + 2*p], wr[base + 2*p + 1]);
            }
            sW[(s * 4 + nt) * 64 + lane] = t.q4;
        }
    }
    __syncthreads();

    float b1v[4], w2v[4];
    #pragma unroll
    for (int nt = 0; nt < 4; ++nt) {
        b1v[nt] = b1[nt * 16 + c];
        w2v[nt] = W2[nt * 16 + c];
    }
    const float b2s = b2[0];

    const int ntiles = (E + 15) >> 4;
    int t = wave;
    if (t >= ntiles) return;

    auto ldidx = [&](int tt_, int& s, int& d) {
        if (tt_ >= ntiles) tt_ = t;
        int em = (tt_ << 4) + c; if (em > E - 1) em = E - 1;
        s = ei[em]; d = ei[E + em];
    };

    int sC, dC;
    ldidx(t, sC, dC);

    for (; t < ntiles; t += nwv) {
        // ---- gather (serial; 6 resident waves hide the latency) ----
        Q hI, mI, hJ, mJ;
        if constexpr (PACK) {
            const uint4* pi = rec + (size_t)sC * 8 + q * 2;
            const uint4* pj = rec + (size_t)dC * 8 + q * 2;
            hI.v = pi[0]; mI.v = pi[1];
            hJ.v = pj[0]; mJ.v = pj[1];
        } else {
            const uint4* pi = (const uint4*)(x + (size_t)sC * DD + q * 8);
            const uint4* pj = (const uint4*)(x + (size_t)dC * DD + q * 8);
            hI.v = pi[0]; mI.v = pi[1];
            hJ.v = pj[0]; mJ.v = pj[1];
        }
        // idx prefetch for next tile (2 regs; issues before the vmcnt wait)
        int sN, dN;
        ldidx(t + nwv, sN, dN);

        // ---- decode both sides -> fp32 x + bf16 log A-frags ----
        float xiv[8], xjv[8];
        bf16x8 aLi, aLj;
        if constexpr (PACK) {
            U8 L;
            #pragma unroll
            for (int p = 0; p < 4; ++p) {
                float lo = __builtin_bit_cast(float, hI.u[p] << 16);
                float hi = __builtin_bit_cast(float, hI.u[p] & 0xffff0000u);
                unsigned xb = (p < 2) ? mI.u[0] : mI.u[1];
                xv_set: ;
                float m0 = ubyte(xb, (2 * p) & 3);
                float m1 = ubyte(xb, (2 * p + 1) & 3);
                xiv[2 * p]     = fmaf(lo * MSC, m0, lo);
                xiv[2 * p + 1] = fmaf(hi * MSC, m1, hi);
            }
            #pragma unroll
            for (int p = 0; p < 4; ++p) {
                unsigned lb = (p < 2) ? mI.u[2] : mI.u[3];
                float l0 = fmaf(ubyte(lb, (2 * p) & 3),     LXIV, LXLO);
                float l1 = fmaf(ubyte(lb, (2 * p + 1) & 3), LXIV, LXLO);
                L.u[p] = pk_tr(l0, l1);
            }
            aLi = L.v;
            #pragma unroll
            for (int p = 0; p < 4; ++p) {
                float lo = __builtin_bit_cast(float, hJ.u[p] << 16);
                float hi = __builtin_bit_cast(float, hJ.u[p] & 0xffff0000u);
                unsigned xb = (p < 2) ? mJ.u[0] : mJ.u[1];
                float m0 = ubyte(xb, (2 * p) & 3);
                float m1 = ubyte(xb, (2 * p + 1) & 3);
                xjv[2 * p]     = fmaf(lo * MSC, m0, lo);
                xjv[2 * p + 1] = fmaf(hi * MSC, m1, hi);
            }
            #pragma unroll
            for (int p = 0; p < 4; ++p) {
                unsigned lb = (p < 2) ? mJ.u[2] : mJ.u[3];
                float l0 = fmaf(ubyte(lb, (2 * p) & 3),     LXIV, LXLO);
                float l1 = fmaf(ubyte(lb, (2 * p + 1) & 3), LXIV, LXLO);
                L.u[p] = pk_tr(l0, l1);
            }
            aLj = L.v;
        } else {
            #pragma unroll
            for (int p = 0; p < 4; ++p) { xiv[p] = hI.f[p]; xiv[4 + p] = mI.f[p]; }
            #pragma unroll
            for (int p = 0; p < 4; ++p) { xjv[p] = hJ.f[p]; xjv[4 + p] = mJ.f[p]; }
            U8 ti, tj;
            #pragma unroll
            for (int p = 0; p < 4; ++p) {
                ti.u[p] = pk_rne(__logf(xiv[2*p] + EPSF), __logf(xiv[2*p+1] + EPSF));
                tj.u[p] = pk_rne(__logf(xjv[2*p] + EPSF), __logf(xjv[2*p+1] + EPSF));
            }
            aLi = ti.v; aLj = tj.v;
        }
        // -lxj: bf16 sign flip on the A side (replaces a WLn weight set)
        U8 nj; nj.v = aLj;
        #pragma unroll
        for (int p = 0; p < 4; ++p) nj.u[p] ^= 0x80008000u;

        // ---- features -> packed A-fragments ----
        U8 R, Rl, Aa, Dd;
        #pragma unroll
        for (int p = 0; p < 4; ++p) {
            float a0 = xiv[2*p], a1 = xiv[2*p+1];
            float c0 = xjv[2*p], c1 = xjv[2*p+1];
            float r0 = a0 * __builtin_amdgcn_rcpf(c0 + EPSF);
            float r1 = a1 * __builtin_amdgcn_rcpf(c1 + EPSF);
            float d0 = fabsf(a0 - c0), d1 = fabsf(a1 - c1);
            float g0 = d0 * __builtin_amdgcn_rcpf(fmaxf(a0, c0) + EPSF);
            float g1 = d1 * __builtin_amdgcn_rcpf(fmaxf(a1, c1) + EPSF);
            R.u[p]  = pk_tr(r0, r1);
            Rl.u[p] = pk_tr(r0 - hi_f32(r0), r1 - hi_f32(r1));
            Aa.u[p] = pk_tr(d0, d1);
            Dd.u[p] = pk_tr(g0, g1);
        }

        // opaque offset: stops LICM hoisting weight ds_reads into registers
        int off = lane;
        asm volatile("" : "+v"(off));

        f32x4 acc[4];
        #pragma unroll
        for (int nt = 0; nt < 4; ++nt) {
            acc[nt][0] = b1v[nt]; acc[nt][1] = b1v[nt];
            acc[nt][2] = b1v[nt]; acc[nt][3] = b1v[nt];
        }
        #pragma unroll
        for (int nt = 0; nt < 4; ++nt) {
            U8 w0h; w0h.q4 = sW[(0 * 4 + nt) * 64 + off];
            U8 w0l; w0l.q4 = sW[(1 * 4 + nt) * 64 + off];
            U8 wL;  wL.q4  = sW[(2 * 4 + nt) * 64 + off];
            U8 wA;  wA.q4  = sW[(3 * 4 + nt) * 64 + off];
            U8 wD;  wD.q4  = sW[(4 * 4 + nt) * 64 + off];
            acc[nt] = __builtin_amdgcn_mfma_f32_16x16x32_bf16(R.v,  w0h.v, acc[nt], 0, 0, 0);
            acc[nt] = __builtin_amdgcn_mfma_f32_16x16x32_bf16(Rl.v, w0h.v, acc[nt], 0, 0, 0);
            acc[nt] = __builtin_amdgcn_mfma_f32_16x16x32_bf16(R.v,  w0l.v, acc[nt], 0, 0, 0);
            acc[nt] = __builtin_amdgcn_mfma_f32_16x16x32_bf16(aLi,  wL.v,  acc[nt], 0, 0, 0);
            acc[nt] = __builtin_amdgcn_mfma_f32_16x16x32_bf16(nj.v, wL.v,  acc[nt], 0, 0, 0);
            acc[nt] = __builtin_amdgcn_mfma_f32_16x16x32_bf16(Aa.v, wA.v,  acc[nt], 0, 0, 0);
            acc[nt] = __builtin_amdgcn_mfma_f32_16x16x32_bf16(Dd.v, wD.v,  acc[nt], 0, 0, 0);
        }

        // ---- layer 2 + reduce: lane holds h[edge=q*4+r][hid=nt*16+c] ----
        float p4[4];
        #pragma unroll
        for (int r = 0; r < 4; ++r) {
            float pp = 0.f;
            #pragma unroll
            for (int nt = 0; nt < 4; ++nt)
                pp = fmaf(fmaxf(acc[nt][r], 0.f), w2v[nt], pp);
            pp += __shfl_xor(pp, 1);
            pp += __shfl_xor(pp, 2);
            pp += __shfl_xor(pp, 4);
            pp += __shfl_xor(pp, 8);
            p4[r] = pp;
        }
        if (c < 4) {
            const int e = (t << 4) + q * 4 + c;
            if (e < E) {
                float v = (c == 0) ? p4[0] : (c == 1) ? p4[1] : (c == 2) ? p4[2] : p4[3];
                out[e] = v + b2s;
            }
        }

        sC = sN; dC = dN;
    }
}

extern "C" void kernel_launch(void* const* d_in, const int* in_sizes, int n_in,
                              void* d_out, int out_size, void* d_ws, size_t ws_size,
                              hipStream_t stream)
{
    const float* x   = (const float*)d_in[0];
    const int*   ei  = (const int*)  d_in[1];
    const float* W1  = (const float*)d_in[2];
    const float* b1  = (const float*)d_in[3];
    const float* W2  = (const float*)d_in[4];
    const float* b2  = (const float*)d_in[5];
    float* out = (float*)d_out;

    const int E  = out_size;       // 1,000,000
    const int Nd = in_sizes[0];    // N*D = 3,200,000
    uint4* rec = (uint4*)d_ws;     // N * 128 bytes = Nd * 4 bytes

    const bool pack = ws_size >= (size_t)Nd * 4 && (Nd % 8) == 0;
    if (pack) {
        const int nchunk = Nd / 8;
        prep_pack<<<(nchunk + 255) / 256, 256, 0, stream>>>(x, rec, nchunk);
        edge_bias_mfma<1><<<2048, 256, 0, stream>>>(x, ei, W1, b1, W2, b2, rec, out, E);
    } else {
        edge_bias_mfma<0><<<2048, 256, 0, stream>>>(x, ei, W1, b1, W2, b2, rec, out, E);
    }
}

// Round 16
// 131.336 us; speedup vs baseline: 2.0498x; 1.1172x over previous
//
#include <hip/hip_runtime.h>

// NumericalBiasModule: out[e] = b2 + W2 · relu(W1 · rel(x[src], x[dst]) + b1)
// rel = [ratio | log_ratio | abs_diff | rel_diff], 128 features.
//
// MFMA tile (validated r4-r12): 16 edges/wave, mfma_f32_16x16x32_bf16.
// lane = (m=lane&15 edge, q=lane>>4 k-chunk); A-frag[j] = feat[m][q*8+j];
// C/D: col=lane&15 (hid), row=q*4+reg (edge).
//
// Structure = r12 EXACT (best validated: kernel 72us, VGPR 56, no spill):
// packed node record (1 line/side: xh bf16[8] | xl8 u8[8] mantissa ext |
// lu8 u8[8] log-quant), 20KB LDS weight image read just-in-time,
// depth-1 gather pipeline, __launch_bounds__(256,4).
// (r13/r14/r15 established min-waves>=6 always hits the allocator spill
// cliff -> occupancy axis is closed; 4 waves is the stable state.)
//
// Round-16 change: epilogue reduction via DPP row_ror adds instead of
// __shfl_xor. The 16-lane butterfly is 16 ds_bpermute ops (~30-40cyc DS-pipe
// each, 4-deep serial chains + lgkm waits). Rotation-based log-step
// reduction (ror 1,2,4,8 within the 16-lane row) is algebraically complete
// for commutative add and runs on the full-rate VALU pipe (~4-8cyc, no DS).
// Also keeps r13's pk_tr log-decode trim (absmax-validated 2.0).

#define DD    32
#define HID   64
#define RELF  128
#define EPSF  1e-8f
#define LXLO  -18.420681f          // log(1e-8)
#define LXSC  13.843137f           // 255 / 18.420681
#define LXIV  0.07223796f          // 18.420681 / 255
#define MSC   3.0517578125e-05f    // 2^-15

typedef short  bf16x8 __attribute__((ext_vector_type(8)));
typedef float  f32x4  __attribute__((ext_vector_type(4)));

union U8 { unsigned u[4]; bf16x8 v; uint4 q4; };
union Q  { uint4 v; unsigned u[4]; float f[4]; };

static __device__ __forceinline__ unsigned pk_tr(float lo, float hi) {
    return __builtin_amdgcn_perm(__builtin_bit_cast(unsigned, hi),
                                 __builtin_bit_cast(unsigned, lo), 0x07060302u);
}
static __device__ __forceinline__ unsigned rne_bits(float f) {
    unsigned u = __builtin_bit_cast(unsigned, f);
    return u + 0x7fffu + ((u >> 16) & 1u);
}
static __device__ __forceinline__ unsigned pk_rne(float lo, float hi) {
    return __builtin_amdgcn_perm(rne_bits(hi), rne_bits(lo), 0x07060302u);
}
static __device__ __forceinline__ float hi_f32(float f) {
    return __builtin_bit_cast(float, __builtin_bit_cast(unsigned, f) & 0xffff0000u);
}
static __device__ __forceinline__ float ubyte(unsigned w, int b) {
    return (float)((w >> (8 * b)) & 0xffu);   // folds to v_cvt_f32_ubyteN
}
static __device__ __forceinline__ unsigned q8(float v) {
    int u = (int)(v + 0.5f);
    return (unsigned)(u > 255 ? 255 : (u < 0 ? 0 : u));
}
// pp += row_ror<N>(pp): within-16-lane rotate-add on the VALU pipe (DPP)
template <int CTRL>
static __device__ __forceinline__ float dpp_ror_add(float pp) {
    int s = __builtin_bit_cast(int, pp);
    int t = __builtin_amdgcn_update_dpp(0, s, CTRL, 0xf, 0xf, true);
    return pp + __builtin_bit_cast(float, t);
}

// ---- prep: one thread per (node, q) 8-dim chunk ----
__global__ __launch_bounds__(256)
void prep_pack(const float* __restrict__ x, uint4* __restrict__ rec, int nchunk)
{
    int i = blockIdx.x * blockDim.x + threadIdx.x;   // chunk = node*4 + q
    if (i >= nchunk) return;
    const float4* xp = (const float4*)(x + (size_t)i * 8);
    float4 v0 = xp[0], v1 = xp[1];
    float xv[8] = {v0.x, v0.y, v0.z, v0.w, v1.x, v1.y, v1.z, v1.w};

    unsigned xh[4];
    #pragma unroll
    for (int p = 0; p < 4; ++p) xh[p] = pk_tr(xv[2*p], xv[2*p+1]);

    unsigned xl[2] = {0u, 0u}, lu[2] = {0u, 0u};
    #pragma unroll
    for (int e = 0; e < 8; ++e) {
        float a  = xv[e];
        float ah = hi_f32(a);
        float f  = 0.f;
        if (ah > 0.f)
            f = (a * __builtin_amdgcn_rcpf(ah) - 1.f) * 32768.f;   // 2^15
        xl[e >> 2] |= q8(f) << (8 * (e & 3));
        float lxe = __logf(a + EPSF);
        lu[e >> 2] |= q8((lxe - LXLO) * LXSC) << (8 * (e & 3));
    }

    uint4 r0; r0.x = xh[0]; r0.y = xh[1]; r0.z = xh[2]; r0.w = xh[3];
    uint4 r1; r1.x = xl[0]; r1.y = xl[1]; r1.z = lu[0]; r1.w = lu[1];
    rec[2 * i]     = r0;
    rec[2 * i + 1] = r1;
}

// PACK=1: packed records (2 lines/edge). PACK=0: raw x + per-edge logf.
template <int PACK>
__global__ __launch_bounds__(256, 4)
void edge_bias_mfma(const float* __restrict__ x,
                    const int*   __restrict__ ei,     // [2, E]
                    const float* __restrict__ W1,     // [64, 128]
                    const float* __restrict__ b1,
                    const float* __restrict__ W2,
                    const float* __restrict__ b2,
                    const uint4* __restrict__ rec,    // [N, 8] packed
                    float* __restrict__ out,
                    int E)
{
    const int lane = threadIdx.x & 63;
    const int wv   = threadIdx.x >> 6;
    const int wave = (blockIdx.x * blockDim.x + threadIdx.x) >> 6;
    const int nwv  = (gridDim.x * blockDim.x) >> 6;
    const int c = lane & 15;      // edge-in-tile (A) / hid-col (C)
    const int q = lane >> 4;      // k-chunk (A,B) / row-quad (C)

    // ---- LDS weight image: 5 sets x 4 nt = 20 frags x 1KB (r11/r12) ----
    // 0: W0h (ratio hi)  1: W0l (ratio lo)  2: WL (log)  3: WA  4: WD
    __shared__ uint4 sW[20 * 64];
    for (int s = wv; s < 5; s += 4) {
        #pragma unroll
        for (int nt = 0; nt < 4; ++nt) {
            const float* wr = W1 + (nt * 16 + c) * RELF + q * 8;
            U8 t;
            if (s == 0) {
                #pragma unroll
                for (int p = 0; p < 4; ++p)
                    t.u[p] = pk_tr(wr[2*p], wr[2*p+1]);
            } else if (s == 1) {
                #pragma unroll
                for (int p = 0; p < 4; ++p) {
                    float w0 = wr[2*p], w1 = wr[2*p+1];
                    t.u[p] = pk_rne(w0 - hi_f32(w0), w1 - hi_f32(w1));
                }
            } else {
                const int base = (s == 2) ? 32 : (s == 3) ? 64 : 96;
                #pragma unroll
                for (int p = 0; p < 4; ++p)
                    t.u[p] = pk_rne(wr[base + 2*p], wr[base + 2*p + 1]);
            }
            sW[(s * 4 + nt) * 64 + lane] = t.q4;
        }
    }
    __syncthreads();

    float b1v[4], w2v[4];
    #pragma unroll
    for (int nt = 0; nt < 4; ++nt) {
        b1v[nt] = b1[nt * 16 + c];
        w2v[nt] = W2[nt * 16 + c];
    }
    const float b2s = b2[0];

    const int ntiles = (E + 15) >> 4;
    int t = wave;
    if (t >= ntiles) return;

    auto ldidx = [&](int tt_, int& s, int& d) {
        if (tt_ >= ntiles) tt_ = t;
        int em = (tt_ << 4) + c; if (em > E - 1) em = E - 1;
        s = ei[em]; d = ei[E + em];
    };
    auto gather = [&](int s, int d, Q& hi_, Q& mi_, Q& hj_, Q& mj_) {
        if constexpr (PACK) {
            const uint4* pi = rec + (size_t)s * 8 + q * 2;
            const uint4* pj = rec + (size_t)d * 8 + q * 2;
            hi_.v = pi[0]; mi_.v = pi[1];
            hj_.v = pj[0]; mj_.v = pj[1];
        } else {
            const uint4* pi = (const uint4*)(x + (size_t)s * DD + q * 8);
            const uint4* pj = (const uint4*)(x + (size_t)d * DD + q * 8);
            hi_.v = pi[0]; mi_.v = pi[1];
            hj_.v = pj[0]; mj_.v = pj[1];
        }
    };
    // decode one packed side -> 8 fp32 x + bf16 log A-frag
    auto decode = [&](const Q& h, const Q& m, float* xv, bf16x8& lfrag) {
        #pragma unroll
        for (int p = 0; p < 4; ++p) {
            float lo = __builtin_bit_cast(float, h.u[p] << 16);
            float hi = __builtin_bit_cast(float, h.u[p] & 0xffff0000u);
            unsigned xb = (p < 2) ? m.u[0] : m.u[1];
            float m0 = ubyte(xb, (2 * p) & 3);
            float m1 = ubyte(xb, (2 * p + 1) & 3);
            xv[2 * p]     = fmaf(lo * MSC, m0, lo);
            xv[2 * p + 1] = fmaf(hi * MSC, m1, hi);
        }
        U8 L;
        #pragma unroll
        for (int p = 0; p < 4; ++p) {
            unsigned lb = (p < 2) ? m.u[2] : m.u[3];
            float l0 = fmaf(ubyte(lb, (2 * p) & 3),     LXIV, LXLO);
            float l1 = fmaf(ubyte(lb, (2 * p + 1) & 3), LXIV, LXLO);
            L.u[p] = pk_tr(l0, l1);   // truncate: lx already quantized at 0.036
        }
        lfrag = L.v;
    };

    auto compute = [&](int tc, const Q& hI, const Q& mI, const Q& hJ, const Q& mJ) {
        float xiv[8], xjv[8];
        bf16x8 aLi, aLj;
        if constexpr (PACK) {
            decode(hI, mI, xiv, aLi);
            decode(hJ, mJ, xjv, aLj);
        } else {
            #pragma unroll
            for (int p = 0; p < 4; ++p) { xiv[p] = hI.f[p]; xiv[4 + p] = mI.f[p]; }
            #pragma unroll
            for (int p = 0; p < 4; ++p) { xjv[p] = hJ.f[p]; xjv[4 + p] = mJ.f[p]; }
            U8 ti, tj;
            #pragma unroll
            for (int p = 0; p < 4; ++p) {
                ti.u[p] = pk_rne(__logf(xiv[2*p] + EPSF), __logf(xiv[2*p+1] + EPSF));
                tj.u[p] = pk_rne(__logf(xjv[2*p] + EPSF), __logf(xjv[2*p+1] + EPSF));
            }
            aLi = ti.v; aLj = tj.v;
        }
        // -lxj: bf16 sign flip on the A side (replaces a WLn weight set)
        U8 nj; nj.v = aLj;
        #pragma unroll
        for (int p = 0; p < 4; ++p) nj.u[p] ^= 0x80008000u;

        U8 R, Rl, Aa, Dd;
        #pragma unroll
        for (int p = 0; p < 4; ++p) {
            float a0 = xiv[2*p], a1 = xiv[2*p+1];
            float c0 = xjv[2*p], c1 = xjv[2*p+1];
            float r0 = a0 * __builtin_amdgcn_rcpf(c0 + EPSF);
            float r1 = a1 * __builtin_amdgcn_rcpf(c1 + EPSF);
            float d0 = fabsf(a0 - c0), d1 = fabsf(a1 - c1);
            float g0 = d0 * __builtin_amdgcn_rcpf(fmaxf(a0, c0) + EPSF);
            float g1 = d1 * __builtin_amdgcn_rcpf(fmaxf(a1, c1) + EPSF);
            R.u[p]  = pk_tr(r0, r1);
            Rl.u[p] = pk_tr(r0 - hi_f32(r0), r1 - hi_f32(r1));
            Aa.u[p] = pk_tr(d0, d1);
            Dd.u[p] = pk_tr(g0, g1);
        }

        // opaque offset: stops LICM hoisting weight ds_reads into registers
        int off = lane;
        asm volatile("" : "+v"(off));
        auto ldfrag = [&](int s, int nt) {
            U8 w; w.q4 = sW[(s * 4 + nt) * 64 + off];
            return w.v;
        };

        f32x4 acc[4];
        #pragma unroll
        for (int nt = 0; nt < 4; ++nt) {
            acc[nt][0] = b1v[nt]; acc[nt][1] = b1v[nt];
            acc[nt][2] = b1v[nt]; acc[nt][3] = b1v[nt];
        }
        #pragma unroll
        for (int nt = 0; nt < 4; ++nt) {
            bf16x8 fW0h = ldfrag(0, nt);
            bf16x8 fW0l = ldfrag(1, nt);
            bf16x8 fWL  = ldfrag(2, nt);
            bf16x8 fWA  = ldfrag(3, nt);
            bf16x8 fWD  = ldfrag(4, nt);
            acc[nt] = __builtin_amdgcn_mfma_f32_16x16x32_bf16(R.v,  fW0h, acc[nt], 0, 0, 0);
            acc[nt] = __builtin_amdgcn_mfma_f32_16x16x32_bf16(Rl.v, fW0h, acc[nt], 0, 0, 0);
            acc[nt] = __builtin_amdgcn_mfma_f32_16x16x32_bf16(R.v,  fW0l, acc[nt], 0, 0, 0);
            acc[nt] = __builtin_amdgcn_mfma_f32_16x16x32_bf16(aLi,  fWL,  acc[nt], 0, 0, 0);
            acc[nt] = __builtin_amdgcn_mfma_f32_16x16x32_bf16(nj.v, fWL,  acc[nt], 0, 0, 0);
            acc[nt] = __builtin_amdgcn_mfma_f32_16x16x32_bf16(Aa.v, fWA,  acc[nt], 0, 0, 0);
            acc[nt] = __builtin_amdgcn_mfma_f32_16x16x32_bf16(Dd.v, fWD,  acc[nt], 0, 0, 0);
        }

        // ---- layer 2 + reduce over the 16-lane row via DPP rotate-adds ----
        // lane holds h[edge=q*4+r][hid=nt*16+c] in acc[nt][r]
        float p4[4];
        #pragma unroll
        for (int r = 0; r < 4; ++r) {
            float pp = 0.f;
            #pragma unroll
            for (int nt = 0; nt < 4; ++nt)
                pp = fmaf(fmaxf(acc[nt][r], 0.f), w2v[nt], pp);
            pp = dpp_ror_add<0x121>(pp);   // row_ror:1
            pp = dpp_ror_add<0x122>(pp);   // row_ror:2
            pp = dpp_ror_add<0x124>(pp);   // row_ror:4
            pp = dpp_ror_add<0x128>(pp);   // row_ror:8
            p4[r] = pp;                    // all 16 lanes hold the row sum
        }
        if (c < 4) {
            const int e = (tc << 4) + q * 4 + c;
            if (e < E) {
                float v = (c == 0) ? p4[0] : (c == 1) ? p4[1] : (c == 2) ? p4[2] : p4[3];
                out[e] = v + b2s;
            }
        }
    };

    // ---- depth-1 pipeline: idx 2 ahead, gathers 1 ahead ----
    Q hiC, miC, hjC, mjC;
    int srcN, dstN;
    { int s, d; ldidx(t, s, d); gather(s, d, hiC, miC, hjC, mjC); }
    ldidx(t + nwv, srcN, dstN);

    for (; t < ntiles; t += nwv) {
        Q hiN, miN, hjN, mjN;
        gather(srcN, dstN, hiN, miN, hjN, mjN);       // tile t+nwv
        int srcN2, dstN2;
        ldidx(t + 2 * nwv, srcN2, dstN2);

        compute(t, hiC, miC, hjC, mjC);

        hiC = hiN; miC = miN; hjC = hjN; mjC = mjN;
        srcN = srcN2; dstN = dstN2;
    }
}

extern "C" void kernel_launch(void* const* d_in, const int* in_sizes, int n_in,
                              void* d_out, int out_size, void* d_ws, size_t ws_size,
                              hipStream_t stream)
{
    const float* x   = (const float*)d_in[0];
    const int*   ei  = (const int*)  d_in[1];
    const float* W1  = (const float*)d_in[2];
    const float* b1  = (const float*)d_in[3];
    const float* W2  = (const float*)d_in[4];
    const float* b2  = (const float*)d_in[5];
    float* out = (float*)d_out;

    const int E  = out_size;       // 1,000,000
    const int Nd = in_sizes[0];    // N*D = 3,200,000
    uint4* rec = (uint4*)d_ws;     // N * 128 bytes = Nd * 4 bytes

    const bool pack = ws_size >= (size_t)Nd * 4 && (Nd % 8) == 0;
    if (pack) {
        const int nchunk = Nd / 8;
        prep_pack<<<(nchunk + 255) / 256, 256, 0, stream>>>(x, rec, nchunk);
        edge_bias_mfma<1><<<2048, 256, 0, stream>>>(x, ei, W1, b1, W2, b2, rec, out, E);
    } else {
        edge_bias_mfma<0><<<2048, 256, 0, stream>>>(x, ei, W1, b1, W2, b2, rec, out, E);
    }
}

// Round 17
// 130.684 us; speedup vs baseline: 2.0600x; 1.0050x over previous
//
#include <hip/hip_runtime.h>

// NumericalBiasModule: out[e] = b2 + W2 · relu(W1 · rel(x[src], x[dst]) + b1)
// rel = [ratio | log_ratio | abs_diff | rel_diff], 128 features.
//
// MFMA tile (validated r4-r16): 16 edges/wave, mfma_f32_16x16x32_bf16.
// lane = (m=lane&15 edge, q=lane>>4 k-chunk); A-frag[j] = feat[m][q*8+j];
// C/D: col=lane&15 (hid), row=q*4+reg (edge).
//
// Structure (validated r16, kernel 64.7us, VGPR 52, absmax 2.0): packed node
// record (1 line/side: xh bf16[8] | xl8 u8[8] mantissa ext | lu8 u8[8]
// log-quant), 20KB LDS weight image read just-in-time, DPP row_ror epilogue,
// __launch_bounds__(256,4).
//
// Round-17 change: depth-2 gather pipeline (r8's A/B-slot skeleton). r8's
// depth-2 was neutral because the kernel then sat AT the ~2.9TB/s random-line
// service wall (rate limit; ILP can't help). r16 runs at 1.5TB/s -- latency/
// queueing-bound -- and the DPP rewrite freed the registers (52 vs r8's 100).
// 2 tiles in flight per wave x 4 waves = 8 per SIMD. +16 regs of buffers,
// ~70-85 total, safely under the (256,4) cap of 128 -> no allocator cliff.

#define DD    32
#define HID   64
#define RELF  128
#define EPSF  1e-8f
#define LXLO  -18.420681f          // log(1e-8)
#define LXSC  13.843137f           // 255 / 18.420681
#define LXIV  0.07223796f          // 18.420681 / 255
#define MSC   3.0517578125e-05f    // 2^-15

typedef short  bf16x8 __attribute__((ext_vector_type(8)));
typedef float  f32x4  __attribute__((ext_vector_type(4)));

union U8 { unsigned u[4]; bf16x8 v; uint4 q4; };
union Q  { uint4 v; unsigned u[4]; float f[4]; };

static __device__ __forceinline__ unsigned pk_tr(float lo, float hi) {
    return __builtin_amdgcn_perm(__builtin_bit_cast(unsigned, hi),
                                 __builtin_bit_cast(unsigned, lo), 0x07060302u);
}
static __device__ __forceinline__ unsigned rne_bits(float f) {
    unsigned u = __builtin_bit_cast(unsigned, f);
    return u + 0x7fffu + ((u >> 16) & 1u);
}
static __device__ __forceinline__ unsigned pk_rne(float lo, float hi) {
    return __builtin_amdgcn_perm(rne_bits(hi), rne_bits(lo), 0x07060302u);
}
static __device__ __forceinline__ float hi_f32(float f) {
    return __builtin_bit_cast(float, __builtin_bit_cast(unsigned, f) & 0xffff0000u);
}
static __device__ __forceinline__ float ubyte(unsigned w, int b) {
    return (float)((w >> (8 * b)) & 0xffu);   // folds to v_cvt_f32_ubyteN
}
static __device__ __forceinline__ unsigned q8(float v) {
    int u = (int)(v + 0.5f);
    return (unsigned)(u > 255 ? 255 : (u < 0 ? 0 : u));
}
// pp += row_ror<N>(pp): within-16-lane rotate-add on the VALU pipe (DPP)
template <int CTRL>
static __device__ __forceinline__ float dpp_ror_add(float pp) {
    int s = __builtin_bit_cast(int, pp);
    int t = __builtin_amdgcn_update_dpp(0, s, CTRL, 0xf, 0xf, true);
    return pp + __builtin_bit_cast(float, t);
}

// ---- prep: one thread per (node, q) 8-dim chunk ----
__global__ __launch_bounds__(256)
void prep_pack(const float* __restrict__ x, uint4* __restrict__ rec, int nchunk)
{
    int i = blockIdx.x * blockDim.x + threadIdx.x;   // chunk = node*4 + q
    if (i >= nchunk) return;
    const float4* xp = (const float4*)(x + (size_t)i * 8);
    float4 v0 = xp[0], v1 = xp[1];
    float xv[8] = {v0.x, v0.y, v0.z, v0.w, v1.x, v1.y, v1.z, v1.w};

    unsigned xh[4];
    #pragma unroll
    for (int p = 0; p < 4; ++p) xh[p] = pk_tr(xv[2*p], xv[2*p+1]);

    unsigned xl[2] = {0u, 0u}, lu[2] = {0u, 0u};
    #pragma unroll
    for (int e = 0; e < 8; ++e) {
        float a  = xv[e];
        float ah = hi_f32(a);
        float f  = 0.f;
        if (ah > 0.f)
            f = (a * __builtin_amdgcn_rcpf(ah) - 1.f) * 32768.f;   // 2^15
        xl[e >> 2] |= q8(f) << (8 * (e & 3));
        float lxe = __logf(a + EPSF);
        lu[e >> 2] |= q8((lxe - LXLO) * LXSC) << (8 * (e & 3));
    }

    uint4 r0; r0.x = xh[0]; r0.y = xh[1]; r0.z = xh[2]; r0.w = xh[3];
    uint4 r1; r1.x = xl[0]; r1.y = xl[1]; r1.z = lu[0]; r1.w = lu[1];
    rec[2 * i]     = r0;
    rec[2 * i + 1] = r1;
}

// PACK=1: packed records (2 lines/edge). PACK=0: raw x + per-edge logf.
template <int PACK>
__global__ __launch_bounds__(256, 4)
void edge_bias_mfma(const float* __restrict__ x,
                    const int*   __restrict__ ei,     // [2, E]
                    const float* __restrict__ W1,     // [64, 128]
                    const float* __restrict__ b1,
                    const float* __restrict__ W2,
                    const float* __restrict__ b2,
                    const uint4* __restrict__ rec,    // [N, 8] packed
                    float* __restrict__ out,
                    int E)
{
    const int lane = threadIdx.x & 63;
    const int wv   = threadIdx.x >> 6;
    const int wave = (blockIdx.x * blockDim.x + threadIdx.x) >> 6;
    const int nwv  = (gridDim.x * blockDim.x) >> 6;
    const int c = lane & 15;      // edge-in-tile (A) / hid-col (C)
    const int q = lane >> 4;      // k-chunk (A,B) / row-quad (C)

    // ---- LDS weight image: 5 sets x 4 nt = 20 frags x 1KB (r11/r12) ----
    // 0: W0h (ratio hi)  1: W0l (ratio lo)  2: WL (log)  3: WA  4: WD
    __shared__ uint4 sW[20 * 64];
    for (int s = wv; s < 5; s += 4) {
        #pragma unroll
        for (int nt = 0; nt < 4; ++nt) {
            const float* wr = W1 + (nt * 16 + c) * RELF + q * 8;
            U8 t;
            if (s == 0) {
                #pragma unroll
                for (int p = 0; p < 4; ++p)
                    t.u[p] = pk_tr(wr[2*p], wr[2*p+1]);
            } else if (s == 1) {
                #pragma unroll
                for (int p = 0; p < 4; ++p) {
                    float w0 = wr[2*p], w1 = wr[2*p+1];
                    t.u[p] = pk_rne(w0 - hi_f32(w0), w1 - hi_f32(w1));
                }
            } else {
                const int base = (s == 2) ? 32 : (s == 3) ? 64 : 96;
                #pragma unroll
                for (int p = 0; p < 4; ++p)
                    t.u[p] = pk_rne(wr[base + 2*p], wr[base + 2*p + 1]);
            }
            sW[(s * 4 + nt) * 64 + lane] = t.q4;
        }
    }
    __syncthreads();

    float b1v[4], w2v[4];
    #pragma unroll
    for (int nt = 0; nt < 4; ++nt) {
        b1v[nt] = b1[nt * 16 + c];
        w2v[nt] = W2[nt * 16 + c];
    }
    const float b2s = b2[0];

    const int ntiles = (E + 15) >> 4;
    int t = wave;
    if (t >= ntiles) return;

    auto ldidx = [&](int tt_, int& s, int& d) {
        if (tt_ >= ntiles) tt_ = t;
        int em = (tt_ << 4) + c; if (em > E - 1) em = E - 1;
        s = ei[em]; d = ei[E + em];
    };
    auto gather = [&](int s, int d, Q& hi_, Q& mi_, Q& hj_, Q& mj_) {
        if constexpr (PACK) {
            const uint4* pi = rec + (size_t)s * 8 + q * 2;
            const uint4* pj = rec + (size_t)d * 8 + q * 2;
            hi_.v = pi[0]; mi_.v = pi[1];
            hj_.v = pj[0]; mj_.v = pj[1];
        } else {
            const uint4* pi = (const uint4*)(x + (size_t)s * DD + q * 8);
            const uint4* pj = (const uint4*)(x + (size_t)d * DD + q * 8);
            hi_.v = pi[0]; mi_.v = pi[1];
            hj_.v = pj[0]; mj_.v = pj[1];
        }
    };
    // decode one packed side -> 8 fp32 x + bf16 log A-frag
    auto decode = [&](const Q& h, const Q& m, float* xv, bf16x8& lfrag) {
        #pragma unroll
        for (int p = 0; p < 4; ++p) {
            float lo = __builtin_bit_cast(float, h.u[p] << 16);
            float hi = __builtin_bit_cast(float, h.u[p] & 0xffff0000u);
            unsigned xb = (p < 2) ? m.u[0] : m.u[1];
            float m0 = ubyte(xb, (2 * p) & 3);
            float m1 = ubyte(xb, (2 * p + 1) & 3);
            xv[2 * p]     = fmaf(lo * MSC, m0, lo);
            xv[2 * p + 1] = fmaf(hi * MSC, m1, hi);
        }
        U8 L;
        #pragma unroll
        for (int p = 0; p < 4; ++p) {
            unsigned lb = (p < 2) ? m.u[2] : m.u[3];
            float l0 = fmaf(ubyte(lb, (2 * p) & 3),     LXIV, LXLO);
            float l1 = fmaf(ubyte(lb, (2 * p + 1) & 3), LXIV, LXLO);
            L.u[p] = pk_tr(l0, l1);   // truncate: lx already quantized at 0.036
        }
        lfrag = L.v;
    };

    auto compute = [&](int tc, const Q& hI, const Q& mI, const Q& hJ, const Q& mJ) {
        float xiv[8], xjv[8];
        bf16x8 aLi, aLj;
        if constexpr (PACK) {
            decode(hI, mI, xiv, aLi);
            decode(hJ, mJ, xjv, aLj);
        } else {
            #pragma unroll
            for (int p = 0; p < 4; ++p) { xiv[p] = hI.f[p]; xiv[4 + p] = mI.f[p]; }
            #pragma unroll
            for (int p = 0; p < 4; ++p) { xjv[p] = hJ.f[p]; xjv[4 + p] = mJ.f[p]; }
            U8 ti, tj;
            #pragma unroll
            for (int p = 0; p < 4; ++p) {
                ti.u[p] = pk_rne(__logf(xiv[2*p] + EPSF), __logf(xiv[2*p+1] + EPSF));
                tj.u[p] = pk_rne(__logf(xjv[2*p] + EPSF), __logf(xjv[2*p+1] + EPSF));
            }
            aLi = ti.v; aLj = tj.v;
        }
        // -lxj: bf16 sign flip on the A side (replaces a WLn weight set)
        U8 nj; nj.v = aLj;
        #pragma unroll
        for (int p = 0; p < 4; ++p) nj.u[p] ^= 0x80008000u;

        U8 R, Rl, Aa, Dd;
        #pragma unroll
        for (int p = 0; p < 4; ++p) {
            float a0 = xiv[2*p], a1 = xiv[2*p+1];
            float c0 = xjv[2*p], c1 = xjv[2*p+1];
            float r0 = a0 * __builtin_amdgcn_rcpf(c0 + EPSF);
            float r1 = a1 * __builtin_amdgcn_rcpf(c1 + EPSF);
            float d0 = fabsf(a0 - c0), d1 = fabsf(a1 - c1);
            float g0 = d0 * __builtin_amdgcn_rcpf(fmaxf(a0, c0) + EPSF);
            float g1 = d1 * __builtin_amdgcn_rcpf(fmaxf(a1, c1) + EPSF);
            R.u[p]  = pk_tr(r0, r1);
            Rl.u[p] = pk_tr(r0 - hi_f32(r0), r1 - hi_f32(r1));
            Aa.u[p] = pk_tr(d0, d1);
            Dd.u[p] = pk_tr(g0, g1);
        }

        // opaque offset: stops LICM hoisting weight ds_reads into registers
        int off = lane;
        asm volatile("" : "+v"(off));
        auto ldfrag = [&](int s, int nt) {
            U8 w; w.q4 = sW[(s * 4 + nt) * 64 + off];
            return w.v;
        };

        f32x4 acc[4];
        #pragma unroll
        for (int nt = 0; nt < 4; ++nt) {
            acc[nt][0] = b1v[nt]; acc[nt][1] = b1v[nt];
            acc[nt][2] = b1v[nt]; acc[nt][3] = b1v[nt];
        }
        #pragma unroll
        for (int nt = 0; nt < 4; ++nt) {
            bf16x8 fW0h = ldfrag(0, nt);
            bf16x8 fW0l = ldfrag(1, nt);
            bf16x8 fWL  = ldfrag(2, nt);
            bf16x8 fWA  = ldfrag(3, nt);
            bf16x8 fWD  = ldfrag(4, nt);
            acc[nt] = __builtin_amdgcn_mfma_f32_16x16x32_bf16(R.v,  fW0h, acc[nt], 0, 0, 0);
            acc[nt] = __builtin_amdgcn_mfma_f32_16x16x32_bf16(Rl.v, fW0h, acc[nt], 0, 0, 0);
            acc[nt] = __builtin_amdgcn_mfma_f32_16x16x32_bf16(R.v,  fW0l, acc[nt], 0, 0, 0);
            acc[nt] = __builtin_amdgcn_mfma_f32_16x16x32_bf16(aLi,  fWL,  acc[nt], 0, 0, 0);
            acc[nt] = __builtin_amdgcn_mfma_f32_16x16x32_bf16(nj.v, fWL,  acc[nt], 0, 0, 0);
            acc[nt] = __builtin_amdgcn_mfma_f32_16x16x32_bf16(Aa.v, fWA,  acc[nt], 0, 0, 0);
            acc[nt] = __builtin_amdgcn_mfma_f32_16x16x32_bf16(Dd.v, fWD,  acc[nt], 0, 0, 0);
        }

        // ---- layer 2 + reduce over the 16-lane row via DPP rotate-adds ----
        float p4[4];
        #pragma unroll
        for (int r = 0; r < 4; ++r) {
            float pp = 0.f;
            #pragma unroll
            for (int nt = 0; nt < 4; ++nt)
                pp = fmaf(fmaxf(acc[nt][r], 0.f), w2v[nt], pp);
            pp = dpp_ror_add<0x121>(pp);   // row_ror:1
            pp = dpp_ror_add<0x122>(pp);   // row_ror:2
            pp = dpp_ror_add<0x124>(pp);   // row_ror:4
            pp = dpp_ror_add<0x128>(pp);   // row_ror:8
            p4[r] = pp;                    // all 16 lanes hold the row sum
        }
        if (c < 4) {
            const int e = (tc << 4) + q * 4 + c;
            if (e < E) {
                float v = (c == 0) ? p4[0] : (c == 1) ? p4[1] : (c == 2) ? p4[2] : p4[3];
                out[e] = v + b2s;
            }
        }
    };

    // ---- depth-2 pipeline: slots A (tile t) and B (tile t+nwv) ----
    Q hA, mA, hJA, mJA;      // slot A
    Q hB, mB, hJB, mJB;      // slot B
    int sC, dC;              // idx for tile t+2*nwv (resident)

    { int s, d; ldidx(t,        s, d); gather(s, d, hA, mA, hJA, mJA); }
    { int s, d; ldidx(t + nwv,  s, d); gather(s, d, hB, mB, hJB, mJB); }
    ldidx(t + 2 * nwv, sC, dC);

    for (;;) {
        compute(t, hA, mA, hJA, mJA);
        gather(sC, dC, hA, mA, hJA, mJA);     // tile t+2*nwv into slot A
        ldidx(t + 3 * nwv, sC, dC);
        t += nwv; if (t >= ntiles) break;

        compute(t, hB, mB, hJB, mJB);
        gather(sC, dC, hB, mB, hJB, mJB);     // tile t+2*nwv into slot B
        ldidx(t + 3 * nwv, sC, dC);
        t += nwv; if (t >= ntiles) break;
    }
}

extern "C" void kernel_launch(void* const* d_in, const int* in_sizes, int n_in,
                              void* d_out, int out_size, void* d_ws, size_t ws_size,
                              hipStream_t stream)
{
    const float* x   = (const float*)d_in[0];
    const int*   ei  = (const int*)  d_in[1];
    const float* W1  = (const float*)d_in[2];
    const float* b1  = (const float*)d_in[3];
    const float* W2  = (const float*)d_in[4];
    const float* b2  = (const float*)d_in[5];
    float* out = (float*)d_out;

    const int E  = out_size;       // 1,000,000
    const int Nd = in_sizes[0];    // N*D = 3,200,000
    uint4* rec = (uint4*)d_ws;     // N * 128 bytes = Nd * 4 bytes

    const bool pack = ws_size >= (size_t)Nd * 4 && (Nd % 8) == 0;
    if (pack) {
        const int nchunk = Nd / 8;
        prep_pack<<<(nchunk + 255) / 256, 256, 0, stream>>>(x, rec, nchunk);
        edge_bias_mfma<1><<<2048, 256, 0, stream>>>(x, ei, W1, b1, W2, b2, rec, out, E);
    } else {
        edge_bias_mfma<0><<<2048, 256, 0, stream>>>(x, ei, W1, b1, W2, b2, rec, out, E);
    }
}